// Round 3
// baseline (479.606 us; speedup 1.0000x reference)
//
#include <hip/hip_runtime.h>

typedef unsigned int u32;
typedef unsigned short u16;
typedef __attribute__((ext_vector_type(8))) short s16x8;
typedef __attribute__((ext_vector_type(4))) float f32x4;
typedef __attribute__((ext_vector_type(4))) unsigned int u32x4;
typedef float f32x4a __attribute__((ext_vector_type(4), aligned(8)));  // 8B-aligned 16B load
typedef u32  u32x2a  __attribute__((ext_vector_type(2), aligned(4)));  // 4B-aligned 8B load

#define TBL    524288u
#define TMASK  (TBL - 1u)
#define HPRIME 2654435761u

// res[l] = floor(16 * 1.3819^l); dense (linear) while (res+1)^2 <= 2^19 -> levels 0..11
__device__ constexpr int RESI[16] = {16,22,30,42,58,80,111,153,212,294,406,561,775,1072,1481,2047};

static __device__ __forceinline__ u16 f2bf(float f){            // RNE f32->bf16
  u32 u = __builtin_bit_cast(u32, f);
  return (u16)((u + 0x7fffu + ((u >> 16) & 1u)) >> 16);
}
static __device__ __forceinline__ float bf2f(u16 h){ return __builtin_bit_cast(float, (u32)h << 16); }
static __device__ __forceinline__ float blo(u32 e){ return __builtin_bit_cast(float, (u32)(e << 16)); }
static __device__ __forceinline__ float bhi(u32 e){ return __builtin_bit_cast(float, (u32)(e & 0xffff0000u)); }
static __device__ __forceinline__ u32 packbf2(float a, float b){ return (u32)f2bf(a) | ((u32)f2bf(b) << 16); }
static __device__ __forceinline__ u32 plo(u32 a, u32 b){ return (a & 0xffffu) | (b << 16); }
static __device__ __forceinline__ u32 phi(u32 a, u32 b){ return (a >> 16) | (b & 0xffff0000u); }

#define MFMA(A,B,C) __builtin_amdgcn_mfma_f32_16x16x32_bf16((A),(B),(C),0,0,0)

// R6 pre-pass: fp32 tables (64 MB) -> packed-bf16 tables (32 MB) in d_ws. (R7's split
// conversion + LDS-prefetch REGRESSED 392->450us: global_load_lds bypassed L1, FETCH +70MB,
// and the latency it "hid" was never the bottleneck. Reverted.)
__global__ __launch_bounds__(256) void cvt_tab(const float4* __restrict__ src,
                                               uint2* __restrict__ dst, int n4) {
  for (int i = blockIdx.x*256 + threadIdx.x; i < n4; i += gridDim.x*256) {
    const float4 v = src[i];
    dst[i] = make_uint2(packbf2(v.x, v.y), packbf2(v.z, v.w));
  }
}

// Fused instant-NGP: fp32 hash-grid encode (per-thread) + 34->64->64->3 MLP via bf16-split MFMA.
// All LDS in the main loop is wave-private; ONE __syncthreads outside the loop (wS init).
// OCCUPANCY HISTORY (do not "optimize" blindly):
//   (256,2): VGPR 120, 515 us (R2) -> 443 (R5 paired loads) -> 392 (R6 packed tables)
//   (256,4)/(256,3) forced squeeze W/O eviction: spills, 928/795 us (R3/R4)
//   LDS-prefetch pipeline (R7): 450 us - dead end (L1 bypass, latency wasn't the stall)
//   R8: evict B2l+B3l (40 VGPR) to shared wS, (256,2): VGPR 108, 375 us - but occupancy
//       STUCK at 2 waves/SIMD: arch 108 + MFMA acc regs ~= 172 total, just above 170=512/3.
// R9: evict B2h[c][1] too (16 more VGPR -> ~156 total) AND declare (256,3) to FORCE the
// allocator under 168. LDS 54272 B: 3 blocks/CU = 162816 <= 163840 (1KB margin - do not grow).
// WRITE_SIZE is the spill tripwire: ~27 MB clean; if it jumps, (256,3) failed -> revert.
template<bool PACKED>
__global__ __launch_bounds__(256, 3) void ngp_fused(
    const float2* __restrict__ xq,    // [N] (x,y) fp32
    const float2* __restrict__ tab32, // [16*2^19] (f0,f1) fp32
    const u32*    __restrict__ ctab,  // [16*2^19] packed bf16 pair (d_ws) - PACKED path
    const float*  __restrict__ w1,    // [34][64]
    const float*  __restrict__ w2,    // [64][64]
    const float*  __restrict__ w3,    // [64][3]
    float* __restrict__ out,          // [N][3]
    int iters)
{
  __shared__ __align__(16) u16   encS[256 * 40];   // 32 bf16 features + 8 pad (80 B stride)
  __shared__ __align__(16) float xyS [256 * 2];    // fp32 x,y per point
  __shared__ __align__(16) u32   hS  [4][16 * 68]; // per-wave 16x64 (hi|lo) u32, stride 68 (+4 pad)
  __shared__ __align__(16) s16x8 wS  [14][64];     // shared frags: B2l->c*2+s, B3l->8+s, B2h[c][1]->10+c

  const int tid  = threadIdx.x;
  const int lane = tid & 63;
  const int wv   = tid >> 6;
  const int m    = lane & 15;   // A row / B,C col
  const int q    = lane >> 4;   // k-quad

  // ---- build B-frags from global fp32 weights (one-time; L2-cached) ----
  // Registers keep only what's used most: B1 (layer1), B2h[c][0], B3h.
  // B2l, B3l, B2h[c][1] live in shared LDS (identical across waves; wave 0 writes).
  float w1x[4], w1y[4];
  s16x8 B1[4], B2h0[4], B3h[2];
  #pragma unroll
  for (int c = 0; c < 4; ++c) {
    const int n = c*16 + m;
    w1x[c] = w1[n]; w1y[c] = w1[64 + n];
    s16x8 f1;
    #pragma unroll
    for (int j = 0; j < 8; ++j) {               // B1: feature rows 2..33, K=32 exactly
      const int k = q*8 + j;
      f1[j] = (short)f2bf(w1[(2 + k)*64 + n]);
    }
    B1[c] = f1;
    #pragma unroll
    for (int s = 0; s < 2; ++s) {
      s16x8 fh, fl;
      #pragma unroll
      for (int j = 0; j < 8; ++j) {
        const int k = s*32 + q*8 + j;
        const float v = w2[k*64 + n];
        const u16 h = f2bf(v);
        fh[j] = (short)h; fl[j] = (short)f2bf(v - bf2f(h));
      }
      if (s == 0) B2h0[c] = fh; else if (wv == 0) wS[10 + c][lane] = fh;
      if (wv == 0) wS[c*2 + s][lane] = fl;
    }
  }
  #pragma unroll
  for (int s = 0; s < 2; ++s) {
    s16x8 fh, fl;
    #pragma unroll
    for (int j = 0; j < 8; ++j) {
      const int k = s*32 + q*8 + j;
      const float v = (m < 3) ? w3[k*3 + m] : 0.f;
      const u16 h = f2bf(v);
      fh[j] = (short)h; fl[j] = (short)f2bf(v - bf2f(h));
    }
    B3h[s] = fh;
    if (wv == 0) wS[8 + s][lane] = fl;
  }
  __syncthreads();   // once, outside the main loop: publish wS to all waves

  for (int it = 0; it < iters; ++it) {
    const int base = (blockIdx.x * iters + it) << 8;   // 256 points / iteration

    // ---- phase A: per-thread fp32 encode -> bf16 feature row in LDS ----
    {
      const float2 xy = xq[base + tid];
      ((float2*)xyS)[tid] = xy;
      const float xf = xy.x, yf = xy.y;
      u32 er[16];
      #pragma unroll
      for (int l = 0; l < 16; ++l) {
        const int res = RESI[l];
        const float px = xf * (float)res, py = yf * (float)res;
        const float fx = floorf(px), fy = floorf(py);
        const float wx = px - fx, wy = py - fy;
        const u32 ix = (u32)fx, iy = (u32)fy;
        const float w00 = (1.f-wx)*(1.f-wy), w10 = wx*(1.f-wy);
        const float w01 = (1.f-wx)*wy,       w11 = wx*wy;
        float f0, f1;
        if (l < 12) {                                  // dense: paired corner loads
          const u32 st  = (u32)res + 1u;
          const u32 i00 = ix + iy*st;
          if (PACKED) {
            const u32* t = ctab + (size_t)l * TBL;
            const u32x2a eA = *(const u32x2a*)&t[i00];        // e00 | e10
            const u32x2a eB = *(const u32x2a*)&t[i00 + st];   // e01 | e11
            f0 = blo(eA[0])*w00 + blo(eA[1])*w10 + blo(eB[0])*w01 + blo(eB[1])*w11;
            f1 = bhi(eA[0])*w00 + bhi(eA[1])*w10 + bhi(eB[0])*w01 + bhi(eB[1])*w11;
          } else {
            const float2* t = tab32 + (size_t)l * TBL;
            const f32x4a eA = *(const f32x4a*)&t[i00];        // e00 | e10
            const f32x4a eB = *(const f32x4a*)&t[i00 + st];   // e01 | e11
            f0 = eA[0]*w00 + eA[2]*w10 + eB[0]*w01 + eB[2]*w11;
            f1 = eA[1]*w00 + eA[3]*w10 + eB[1]*w01 + eB[3]*w11;
          }
        } else {                                       // spatial hash, u32 wraparound
          const u32 hy = iy * HPRIME, hy1 = hy + HPRIME;
          const u32 i00 = ( ix        ^ hy ) & TMASK;
          const u32 i10 = ((ix + 1u)  ^ hy ) & TMASK;
          const u32 i01 = ( ix        ^ hy1) & TMASK;
          const u32 i11 = ((ix + 1u)  ^ hy1) & TMASK;
          if (PACKED) {
            const u32* t = ctab + (size_t)l * TBL;
            const u32 e00 = t[i00], e10 = t[i10], e01 = t[i01], e11 = t[i11];
            f0 = blo(e00)*w00 + blo(e10)*w10 + blo(e01)*w01 + blo(e11)*w11;
            f1 = bhi(e00)*w00 + bhi(e10)*w10 + bhi(e01)*w01 + bhi(e11)*w11;
          } else {
            const float2* t = tab32 + (size_t)l * TBL;
            const float2 e00 = t[i00], e10 = t[i10], e01 = t[i01], e11 = t[i11];
            f0 = e00.x*w00 + e10.x*w10 + e01.x*w01 + e11.x*w11;
            f1 = e00.y*w00 + e10.y*w10 + e01.y*w01 + e11.y*w11;
          }
        }
        er[l] = (u32)f2bf(f0) | ((u32)f2bf(f1) << 16);
      }
      uint4* rowp = (uint4*)&encS[tid * 40];
      rowp[0] = make_uint4(er[0],  er[1],  er[2],  er[3]);
      rowp[1] = make_uint4(er[4],  er[5],  er[6],  er[7]);
      rowp[2] = make_uint4(er[8],  er[9],  er[10], er[11]);
      rowp[3] = make_uint4(er[12], er[13], er[14], er[15]);
    }

    // ---- phase B: per-wave MFMA MLP, 4 tiles of 16 points (wave-private, no barriers) ----
    #pragma unroll 1
    for (int t4 = 0; t4 < 4; ++t4) {
      const int rbase = wv*64 + t4*16;
      const s16x8 a1 = *(const s16x8*)&encS[(rbase + m)*40 + q*8];

      float xr[4], yr[4];
      #pragma unroll
      for (int r = 0; r < 4; ++r) {
        const float2 v = ((const float2*)xyS)[rbase + q*4 + r];
        xr[r] = v.x; yr[r] = v.y;
      }

      f32x4 acc[4];
      #pragma unroll
      for (int c = 0; c < 4; ++c) {
        f32x4 z;
        #pragma unroll
        for (int r = 0; r < 4; ++r) z[r] = xr[r]*w1x[c] + yr[r]*w1y[c];  // fp32 x,y path
        acc[c] = MFMA(a1, B1[c], z);
      }

      u32* hw = &hS[wv][0];
      #pragma unroll
      for (int c = 0; c < 4; ++c)
        #pragma unroll
        for (int r = 0; r < 4; ++r) {
          const float h = fmaxf(acc[c][r], 0.f);
          const u16 hi = f2bf(h);
          const u16 lo = f2bf(h - bf2f(hi));
          hw[(q*4 + r)*68 + c*16 + m] = (u32)hi | ((u32)lo << 16);
        }

      uint4 r0 = *(uint4*)&hw[m*68 + q*8];
      uint4 r1 = *(uint4*)&hw[m*68 + q*8 + 4];
      uint4 r2 = *(uint4*)&hw[m*68 + 32 + q*8];
      uint4 r3 = *(uint4*)&hw[m*68 + 32 + q*8 + 4];
      u32x4 t0, t1;
      t0.x=plo(r0.x,r0.y); t0.y=plo(r0.z,r0.w); t0.z=plo(r1.x,r1.y); t0.w=plo(r1.z,r1.w);
      s16x8 hi0 = __builtin_bit_cast(s16x8, t0);
      t1.x=phi(r0.x,r0.y); t1.y=phi(r0.z,r0.w); t1.z=phi(r1.x,r1.y); t1.w=phi(r1.z,r1.w);
      s16x8 lo0 = __builtin_bit_cast(s16x8, t1);
      t0.x=plo(r2.x,r2.y); t0.y=plo(r2.z,r2.w); t0.z=plo(r3.x,r3.y); t0.w=plo(r3.z,r3.w);
      s16x8 hi1 = __builtin_bit_cast(s16x8, t0);
      t1.x=phi(r2.x,r2.y); t1.y=phi(r2.z,r2.w); t1.z=phi(r3.x,r3.y); t1.w=phi(r3.z,r3.w);
      s16x8 lo1 = __builtin_bit_cast(s16x8, t1);

      #pragma unroll
      for (int c = 0; c < 4; ++c) {
        const s16x8 b2h1 = wS[10 + c][lane];    // evicted frags from shared LDS
        const s16x8 b2l0 = wS[c*2 + 0][lane];
        const s16x8 b2l1 = wS[c*2 + 1][lane];
        f32x4 z = {0.f,0.f,0.f,0.f};
        z = MFMA(hi0, B2h0[c], z); z = MFMA(hi1, b2h1, z);
        z = MFMA(lo0, B2h0[c], z); z = MFMA(lo1, b2h1, z);
        z = MFMA(hi0, b2l0,    z); z = MFMA(hi1, b2l1, z);
        acc[c] = z;
      }

      #pragma unroll
      for (int c = 0; c < 4; ++c)
        #pragma unroll
        for (int r = 0; r < 4; ++r) {
          const float h = fmaxf(acc[c][r], 0.f);
          const u16 hi = f2bf(h);
          const u16 lo = f2bf(h - bf2f(hi));
          hw[(q*4 + r)*68 + c*16 + m] = (u32)hi | ((u32)lo << 16);
        }

      r0 = *(uint4*)&hw[m*68 + q*8];
      r1 = *(uint4*)&hw[m*68 + q*8 + 4];
      r2 = *(uint4*)&hw[m*68 + 32 + q*8];
      r3 = *(uint4*)&hw[m*68 + 32 + q*8 + 4];
      t0.x=plo(r0.x,r0.y); t0.y=plo(r0.z,r0.w); t0.z=plo(r1.x,r1.y); t0.w=plo(r1.z,r1.w);
      hi0 = __builtin_bit_cast(s16x8, t0);
      t1.x=phi(r0.x,r0.y); t1.y=phi(r0.z,r0.w); t1.z=phi(r1.x,r1.y); t1.w=phi(r1.z,r1.w);
      lo0 = __builtin_bit_cast(s16x8, t1);
      t0.x=plo(r2.x,r2.y); t0.y=plo(r2.z,r2.w); t0.z=plo(r3.x,r3.y); t0.w=plo(r3.z,r3.w);
      hi1 = __builtin_bit_cast(s16x8, t0);
      t1.x=phi(r2.x,r2.y); t1.y=phi(r2.z,r2.w); t1.z=phi(r3.x,r3.y); t1.w=phi(r3.z,r3.w);
      lo1 = __builtin_bit_cast(s16x8, t1);

      const s16x8 b3l0 = wS[8][lane];
      const s16x8 b3l1 = wS[9][lane];
      f32x4 z = {0.f,0.f,0.f,0.f};
      z = MFMA(hi0, B3h[0], z); z = MFMA(hi1, B3h[1], z);
      z = MFMA(lo0, B3h[0], z); z = MFMA(lo1, B3h[1], z);
      z = MFMA(hi0, b3l0,   z); z = MFMA(hi1, b3l1,   z);

      if (m < 3) {   // C: row = q*4+r, col = m
        #pragma unroll
        for (int r = 0; r < 4; ++r)
          out[(size_t)(base + rbase + q*4 + r)*3 + m] = z[r];
      }
    }
  }
}

extern "C" void kernel_launch(void* const* d_in, const int* in_sizes, int n_in,
                              void* d_out, int out_size, void* d_ws, size_t ws_size,
                              hipStream_t stream) {
  const int N = in_sizes[0] / 2;            // 2^21 points
  const int ITERS = 4;
  const int blocks = N / (256 * ITERS);     // 2048 blocks
  const size_t ctab_bytes = (size_t)16 * TBL * 4;   // 32 MB packed-bf16 tables
  if (ws_size >= ctab_bytes) {
    cvt_tab<<<2048, 256, 0, stream>>>((const float4*)d_in[1], (uint2*)d_ws, (int)(16*TBL/2));
    ngp_fused<true><<<blocks, 256, 0, stream>>>(
        (const float2*)d_in[0], (const float2*)d_in[1], (const u32*)d_ws,
        (const float*)d_in[2], (const float*)d_in[3], (const float*)d_in[4],
        (float*)d_out, ITERS);
  } else {
    ngp_fused<false><<<blocks, 256, 0, stream>>>(
        (const float2*)d_in[0], (const float2*)d_in[1], (const u32*)d_ws,
        (const float*)d_in[2], (const float*)d_in[3], (const float*)d_in[4],
        (float*)d_out, ITERS);
  }
}

// Round 4
// 458.438 us; speedup vs baseline: 1.0462x; 1.0462x over previous
//
#include <hip/hip_runtime.h>

typedef unsigned int u32;
typedef unsigned short u16;
typedef __attribute__((ext_vector_type(8))) short s16x8;
typedef __attribute__((ext_vector_type(4))) float f32x4;
typedef float f32x4a __attribute__((ext_vector_type(4), aligned(8)));  // 8B-aligned 16B load
typedef u32  u32x2a  __attribute__((ext_vector_type(2), aligned(4)));  // 4B-aligned 8B load

#define TBL    524288u
#define TMASK  (TBL - 1u)
#define HPRIME 2654435761u

// res[l] = floor(16 * 1.3819^l); dense (linear) while (res+1)^2 <= 2^19 -> levels 0..11
__device__ constexpr int RESI[16] = {16,22,30,42,58,80,111,153,212,294,406,561,775,1072,1481,2047};

static __device__ __forceinline__ u16 f2bf(float f){            // RNE f32->bf16 (manual)
  u32 u = __builtin_bit_cast(u32, f);
  return (u16)((u + 0x7fffu + ((u >> 16) & 1u)) >> 16);
}
static __device__ __forceinline__ float bf2f(u16 h){ return __builtin_bit_cast(float, (u32)h << 16); }
static __device__ __forceinline__ float blo(u32 e){ return __builtin_bit_cast(float, (u32)(e << 16)); }
static __device__ __forceinline__ float bhi(u32 e){ return __builtin_bit_cast(float, (u32)(e & 0xffff0000u)); }
static __device__ __forceinline__ u32 packbf2(float a, float b){ return (u32)f2bf(a) | ((u32)f2bf(b) << 16); }
// HW packed RNE f32->bf16 (gfx950): D.lo = bf16(a), D.hi = bf16(b). Same rounding as f2bf,
// 1 instruction instead of ~9. No volatile/memory clobber -> scheduler stays free.
static __device__ __forceinline__ u32 cvtpk(float a, float b){
  u32 r; asm("v_cvt_pk_bf16_f32 %0, %1, %2" : "=v"(r) : "v"(a), "v"(b)); return r;
}

#define MFMA(A,B,C) __builtin_amdgcn_mfma_f32_16x16x32_bf16((A),(B),(C),0,0,0)

// R6 pre-pass: fp32 tables (64 MB) -> packed-bf16 tables (32 MB) in d_ws. (R7's split
// conversion + LDS-prefetch REGRESSED 392->450us: global_load_lds bypassed L1, FETCH +70MB,
// and the latency it "hid" was never the bottleneck. Reverted.)
__global__ __launch_bounds__(256) void cvt_tab(const float4* __restrict__ src,
                                               uint2* __restrict__ dst, int n4) {
  for (int i = blockIdx.x*256 + threadIdx.x; i < n4; i += gridDim.x*256) {
    const float4 v = src[i];
    dst[i] = make_uint2(packbf2(v.x, v.y), packbf2(v.z, v.w));
  }
}

// Fused instant-NGP: fp32 hash-grid encode (per-thread) + 34->64->64->3 MLP via bf16-split MFMA.
// All LDS in the main loop is wave-private; ONE __syncthreads outside the loop (wS init).
// OCCUPANCY HISTORY - the 2-waves/SIMD cap is STRUCTURAL, stop pulling this lever:
//   (256,2): VGPR 120, 515 us (R2) -> 443 (R5 paired loads) -> 392 (R6 packed tables)
//   (256,4)/(256,3) squeeze w/o eviction: spills, 928/795 us (R3/R4)
//   LDS-prefetch pipeline (R7): 450 us (L1 bypass; latency wasn't the stall)
//   R8 evict B2l+B3l->LDS, (256,2): VGPR 108, 375 us, occupancy UNchanged (20%)
//   R9 evict B2h1 too + (256,3): VGPR 84 but WRITE 27->45MB (spills), 387 us, occupancy
//      STILL 20% -> cap lives in AGPR/unified-file or LDS granule, not arch VGPRs. Reverted.
// R10: attack VALU instead (38% busy, biggest pipe): (a) v_cvt_pk_bf16_f32 replaces manual
// RNE packs; (b) hi/lo stored as SEPARATE u16 LDS planes (row stride 80 u16 = 160 B ->
// write banks spread by 8 per q-group, conflict-free) so layer-2/3 A-frags are direct
// ds_read_b128 with ZERO plo/phi repack.
template<bool PACKED>
__global__ __launch_bounds__(256, 2) void ngp_fused(
    const float2* __restrict__ xq,    // [N] (x,y) fp32
    const float2* __restrict__ tab32, // [16*2^19] (f0,f1) fp32
    const u32*    __restrict__ ctab,  // [16*2^19] packed bf16 pair (d_ws) - PACKED path
    const float*  __restrict__ w1,    // [34][64]
    const float*  __restrict__ w2,    // [64][64]
    const float*  __restrict__ w3,    // [64][3]
    float* __restrict__ out,          // [N][3]
    int iters)
{
  __shared__ __align__(16) u16   encS[256 * 40];   // 32 bf16 features + 8 pad (80 B stride)
  __shared__ __align__(16) float xyS [256 * 2];    // fp32 x,y per point
  __shared__ __align__(16) u16   hS  [4][2][16*80];// [wave][hi/lo plane][row*80 + neuron]
  __shared__ __align__(16) s16x8 wS  [10][64];     // shared lo-frags: B2l[c][s]->c*2+s, B3l[s]->8+s

  const int tid  = threadIdx.x;
  const int lane = tid & 63;
  const int wv   = tid >> 6;
  const int m    = lane & 15;   // A row / B,C col
  const int q    = lane >> 4;   // k-quad

  // ---- build B-frags from global fp32 weights (one-time; L2-cached) ----
  // Hot frags in registers: B1, B2h (both halves), B3h. Cold lo-frags in shared LDS.
  float w1x[4], w1y[4];
  s16x8 B1[4], B2h[4][2], B3h[2];
  #pragma unroll
  for (int c = 0; c < 4; ++c) {
    const int n = c*16 + m;
    w1x[c] = w1[n]; w1y[c] = w1[64 + n];
    s16x8 f1;
    #pragma unroll
    for (int j = 0; j < 8; ++j) {               // B1: feature rows 2..33, K=32 exactly
      const int k = q*8 + j;
      f1[j] = (short)f2bf(w1[(2 + k)*64 + n]);
    }
    B1[c] = f1;
    #pragma unroll
    for (int s = 0; s < 2; ++s) {
      s16x8 fh, fl;
      #pragma unroll
      for (int j = 0; j < 8; ++j) {
        const int k = s*32 + q*8 + j;
        const float v = w2[k*64 + n];
        const u16 h = f2bf(v);
        fh[j] = (short)h; fl[j] = (short)f2bf(v - bf2f(h));
      }
      B2h[c][s] = fh;
      if (wv == 0) wS[c*2 + s][lane] = fl;
    }
  }
  #pragma unroll
  for (int s = 0; s < 2; ++s) {
    s16x8 fh, fl;
    #pragma unroll
    for (int j = 0; j < 8; ++j) {
      const int k = s*32 + q*8 + j;
      const float v = (m < 3) ? w3[k*3 + m] : 0.f;
      const u16 h = f2bf(v);
      fh[j] = (short)h; fl[j] = (short)f2bf(v - bf2f(h));
    }
    B3h[s] = fh;
    if (wv == 0) wS[8 + s][lane] = fl;
  }
  __syncthreads();   // once, outside the main loop: publish wS to all waves

  u16* const hpl = &hS[wv][0][0];   // hi plane (this wave)
  u16* const lpl = &hS[wv][1][0];   // lo plane (this wave)

  for (int it = 0; it < iters; ++it) {
    const int base = (blockIdx.x * iters + it) << 8;   // 256 points / iteration

    // ---- phase A: per-thread fp32 encode -> bf16 feature row in LDS ----
    {
      const float2 xy = xq[base + tid];
      ((float2*)xyS)[tid] = xy;
      const float xf = xy.x, yf = xy.y;
      u32 er[16];
      #pragma unroll
      for (int l = 0; l < 16; ++l) {
        const int res = RESI[l];
        const float px = xf * (float)res, py = yf * (float)res;
        const float fx = floorf(px), fy = floorf(py);
        const float wx = px - fx, wy = py - fy;
        const u32 ix = (u32)fx, iy = (u32)fy;
        const float w00 = (1.f-wx)*(1.f-wy), w10 = wx*(1.f-wy);
        const float w01 = (1.f-wx)*wy,       w11 = wx*wy;
        float f0, f1;
        if (l < 12) {                                  // dense: paired corner loads
          const u32 st  = (u32)res + 1u;
          const u32 i00 = ix + iy*st;
          if (PACKED) {
            const u32* t = ctab + (size_t)l * TBL;
            const u32x2a eA = *(const u32x2a*)&t[i00];        // e00 | e10
            const u32x2a eB = *(const u32x2a*)&t[i00 + st];   // e01 | e11
            f0 = blo(eA[0])*w00 + blo(eA[1])*w10 + blo(eB[0])*w01 + blo(eB[1])*w11;
            f1 = bhi(eA[0])*w00 + bhi(eA[1])*w10 + bhi(eB[0])*w01 + bhi(eB[1])*w11;
          } else {
            const float2* t = tab32 + (size_t)l * TBL;
            const f32x4a eA = *(const f32x4a*)&t[i00];        // e00 | e10
            const f32x4a eB = *(const f32x4a*)&t[i00 + st];   // e01 | e11
            f0 = eA[0]*w00 + eA[2]*w10 + eB[0]*w01 + eB[2]*w11;
            f1 = eA[1]*w00 + eA[3]*w10 + eB[1]*w01 + eB[3]*w11;
          }
        } else {                                       // spatial hash, u32 wraparound
          const u32 hy = iy * HPRIME, hy1 = hy + HPRIME;
          const u32 i00 = ( ix        ^ hy ) & TMASK;
          const u32 i10 = ((ix + 1u)  ^ hy ) & TMASK;
          const u32 i01 = ( ix        ^ hy1) & TMASK;
          const u32 i11 = ((ix + 1u)  ^ hy1) & TMASK;
          if (PACKED) {
            const u32* t = ctab + (size_t)l * TBL;
            const u32 e00 = t[i00], e10 = t[i10], e01 = t[i01], e11 = t[i11];
            f0 = blo(e00)*w00 + blo(e10)*w10 + blo(e01)*w01 + blo(e11)*w11;
            f1 = bhi(e00)*w00 + bhi(e10)*w10 + bhi(e01)*w01 + bhi(e11)*w11;
          } else {
            const float2* t = tab32 + (size_t)l * TBL;
            const float2 e00 = t[i00], e10 = t[i10], e01 = t[i01], e11 = t[i11];
            f0 = e00.x*w00 + e10.x*w10 + e01.x*w01 + e11.x*w11;
            f1 = e00.y*w00 + e10.y*w10 + e01.y*w01 + e11.y*w11;
          }
        }
        er[l] = cvtpk(f0, f1);                         // 1 instr replaces ~9-op manual pack
      }
      uint4* rowp = (uint4*)&encS[tid * 40];
      rowp[0] = make_uint4(er[0],  er[1],  er[2],  er[3]);
      rowp[1] = make_uint4(er[4],  er[5],  er[6],  er[7]);
      rowp[2] = make_uint4(er[8],  er[9],  er[10], er[11]);
      rowp[3] = make_uint4(er[12], er[13], er[14], er[15]);
    }

    // ---- phase B: per-wave MFMA MLP, 4 tiles of 16 points (wave-private, no barriers) ----
    #pragma unroll 1
    for (int t4 = 0; t4 < 4; ++t4) {
      const int rbase = wv*64 + t4*16;
      const s16x8 a1 = *(const s16x8*)&encS[(rbase + m)*40 + q*8];

      float xr[4], yr[4];
      #pragma unroll
      for (int r = 0; r < 4; ++r) {
        const float2 v = ((const float2*)xyS)[rbase + q*4 + r];
        xr[r] = v.x; yr[r] = v.y;
      }

      f32x4 acc[4];
      #pragma unroll
      for (int c = 0; c < 4; ++c) {
        f32x4 z;
        #pragma unroll
        for (int r = 0; r < 4; ++r) z[r] = xr[r]*w1x[c] + yr[r]*w1y[c];  // fp32 x,y path
        acc[c] = MFMA(a1, B1[c], z);
      }

      // relu + hi/lo bf16 split -> separate u16 planes (direct b128-readable, no repack)
      #pragma unroll
      for (int c = 0; c < 4; ++c)
        #pragma unroll
        for (int r = 0; r < 4; ++r) {
          const float h = fmaxf(acc[c][r], 0.f);
          const u32 hp_ = cvtpk(h, h);                                  // lo16 = bf16(h)
          const float lf = h - __builtin_bit_cast(float, hp_ << 16);
          const u32 lp_ = cvtpk(lf, lf);
          const int idx = (q*4 + r)*80 + c*16 + m;
          hpl[idx] = (u16)hp_;
          lpl[idx] = (u16)lp_;
        }

      s16x8 hi0 = *(const s16x8*)&hpl[m*80 + q*8];
      s16x8 hi1 = *(const s16x8*)&hpl[m*80 + 32 + q*8];
      s16x8 lo0 = *(const s16x8*)&lpl[m*80 + q*8];
      s16x8 lo1 = *(const s16x8*)&lpl[m*80 + 32 + q*8];

      #pragma unroll
      for (int c = 0; c < 4; ++c) {
        const s16x8 b2l0 = wS[c*2 + 0][lane];   // cold lo-frags from shared LDS
        const s16x8 b2l1 = wS[c*2 + 1][lane];
        f32x4 z = {0.f,0.f,0.f,0.f};
        z = MFMA(hi0, B2h[c][0], z); z = MFMA(hi1, B2h[c][1], z);
        z = MFMA(lo0, B2h[c][0], z); z = MFMA(lo1, B2h[c][1], z);
        z = MFMA(hi0, b2l0,      z); z = MFMA(hi1, b2l1,      z);
        acc[c] = z;
      }

      #pragma unroll
      for (int c = 0; c < 4; ++c)
        #pragma unroll
        for (int r = 0; r < 4; ++r) {
          const float h = fmaxf(acc[c][r], 0.f);
          const u32 hp_ = cvtpk(h, h);
          const float lf = h - __builtin_bit_cast(float, hp_ << 16);
          const u32 lp_ = cvtpk(lf, lf);
          const int idx = (q*4 + r)*80 + c*16 + m;
          hpl[idx] = (u16)hp_;
          lpl[idx] = (u16)lp_;
        }

      hi0 = *(const s16x8*)&hpl[m*80 + q*8];
      hi1 = *(const s16x8*)&hpl[m*80 + 32 + q*8];
      lo0 = *(const s16x8*)&lpl[m*80 + q*8];
      lo1 = *(const s16x8*)&lpl[m*80 + 32 + q*8];

      const s16x8 b3l0 = wS[8][lane];
      const s16x8 b3l1 = wS[9][lane];
      f32x4 z = {0.f,0.f,0.f,0.f};
      z = MFMA(hi0, B3h[0], z); z = MFMA(hi1, B3h[1], z);
      z = MFMA(lo0, B3h[0], z); z = MFMA(lo1, B3h[1], z);
      z = MFMA(hi0, b3l0,   z); z = MFMA(hi1, b3l1,   z);

      if (m < 3) {   // C: row = q*4+r, col = m
        #pragma unroll
        for (int r = 0; r < 4; ++r)
          out[(size_t)(base + rbase + q*4 + r)*3 + m] = z[r];
      }
    }
  }
}

extern "C" void kernel_launch(void* const* d_in, const int* in_sizes, int n_in,
                              void* d_out, int out_size, void* d_ws, size_t ws_size,
                              hipStream_t stream) {
  const int N = in_sizes[0] / 2;            // 2^21 points
  const int ITERS = 4;
  const int blocks = N / (256 * ITERS);     // 2048 blocks
  const size_t ctab_bytes = (size_t)16 * TBL * 4;   // 32 MB packed-bf16 tables
  if (ws_size >= ctab_bytes) {
    cvt_tab<<<2048, 256, 0, stream>>>((const float4*)d_in[1], (uint2*)d_ws, (int)(16*TBL/2));
    ngp_fused<true><<<blocks, 256, 0, stream>>>(
        (const float2*)d_in[0], (const float2*)d_in[1], (const u32*)d_ws,
        (const float*)d_in[2], (const float*)d_in[3], (const float*)d_in[4],
        (float*)d_out, ITERS);
  } else {
    ngp_fused<false><<<blocks, 256, 0, stream>>>(
        (const float2*)d_in[0], (const float2*)d_in[1], (const u32*)d_ws,
        (const float*)d_in[2], (const float*)d_in[3], (const float*)d_in[4],
        (float*)d_out, ITERS);
  }
}

// Round 5
// 433.726 us; speedup vs baseline: 1.1058x; 1.0570x over previous
//
#include <hip/hip_runtime.h>

typedef unsigned int u32;
typedef unsigned short u16;
typedef __attribute__((ext_vector_type(8))) short s16x8;
typedef __attribute__((ext_vector_type(4))) float f32x4;
typedef float f32x4a __attribute__((ext_vector_type(4), aligned(8)));  // 8B-aligned 16B load
typedef u32  u32x2a  __attribute__((ext_vector_type(2), aligned(4)));  // 4B-aligned 8B load

#define TBL    524288u
#define TMASK  (TBL - 1u)
#define HPRIME 2654435761u

// res[l] = floor(16 * 1.3819^l); dense (linear) while (res+1)^2 <= 2^19 -> levels 0..11
__device__ constexpr int RESI[16] = {16,22,30,42,58,80,111,153,212,294,406,561,775,1072,1481,2047};

static __device__ __forceinline__ u16 f2bf(float f){            // RNE f32->bf16 (manual)
  u32 u = __builtin_bit_cast(u32, f);
  return (u16)((u + 0x7fffu + ((u >> 16) & 1u)) >> 16);
}
static __device__ __forceinline__ float bf2f(u16 h){ return __builtin_bit_cast(float, (u32)h << 16); }
static __device__ __forceinline__ float blo(u32 e){ return __builtin_bit_cast(float, (u32)(e << 16)); }
static __device__ __forceinline__ float bhi(u32 e){ return __builtin_bit_cast(float, (u32)(e & 0xffff0000u)); }
static __device__ __forceinline__ u32 packbf2(float a, float b){ return (u32)f2bf(a) | ((u32)f2bf(b) << 16); }
// HW packed RNE f32->bf16 (gfx950): D.lo = bf16(a), D.hi = bf16(b). Same rounding as f2bf.
static __device__ __forceinline__ u32 cvtpk(float a, float b){
  u32 r; asm("v_cvt_pk_bf16_f32 %0, %1, %2" : "=v"(r) : "v"(a), "v"(b)); return r;
}

#define MFMA(A,B,C) __builtin_amdgcn_mfma_f32_16x16x32_bf16((A),(B),(C),0,0,0)

// R6 pre-pass: fp32 tables (64 MB) -> packed-bf16 tables (32 MB) in d_ws. (R7's split
// conversion + LDS-prefetch REGRESSED 392->450us: global_load_lds bypassed L1, FETCH +70MB,
// and the latency it "hid" was never the bottleneck. Reverted.)
__global__ __launch_bounds__(256) void cvt_tab(const float4* __restrict__ src,
                                               uint2* __restrict__ dst, int n4) {
  for (int i = blockIdx.x*256 + threadIdx.x; i < n4; i += gridDim.x*256) {
    const float4 v = src[i];
    dst[i] = make_uint2(packbf2(v.x, v.y), packbf2(v.z, v.w));
  }
}

// Fused instant-NGP: fp32 hash-grid encode (per-thread) + 34->64->64->3 MLP via bf16-split MFMA.
// All LDS in the main loop is wave-private; ONE __syncthreads outside the loop (wS init).
// OCCUPANCY MODEL (verified R8/R9/R10): 3 blocks/CU iff arch VGPR <= ~104 (arch + ~64
// unified acc <= 170) AND LDS <= 53248 B (R9's 54272 missed by 1KB -> stuck at 2). Current
// budget: VGPR ~100/104, LDS 53248/53248. DO NOT grow either.
//   (256,2): 515 (R2) -> 443 (R5) -> 392 (R6 packed) -> 375 (R8 evict) -> 363 (R10 cvt_pk
//   + u16 planes, 3 blocks/CU). R3/R4/R9 forced squeezes: spills. R7 LDS-prefetch: dead end.
// R11: (a) hi/lo plane writes were 8-way bank-conflicted (160B row stride ==0 mod 128 ->
// q never changes bank; conflicts 4.7M->17.3M in R10). Fix: XOR-swizzle col^=(q<<3); XOR
// hits col bits 3-4 only -> b128 reads stay contiguous, read addr XORs the data-row's quad
// (m&12)<<1. (b) hash levels 12..15 (8MB packed tables, L2-oversubscribed -> longest
// latency) issue their 16 gathers FIRST into regs; dense levels interp while they fly.
template<bool PACKED>
__global__ __launch_bounds__(256, 2) void ngp_fused(
    const float2* __restrict__ xq,    // [N] (x,y) fp32
    const float2* __restrict__ tab32, // [16*2^19] (f0,f1) fp32
    const u32*    __restrict__ ctab,  // [16*2^19] packed bf16 pair (d_ws) - PACKED path
    const float*  __restrict__ w1,    // [34][64]
    const float*  __restrict__ w2,    // [64][64]
    const float*  __restrict__ w3,    // [64][3]
    float* __restrict__ out,          // [N][3]
    int iters)
{
  __shared__ __align__(16) u16   encS[256 * 40];   // 32 bf16 features + 8 pad (80 B stride)
  __shared__ __align__(16) float xyS [256 * 2];    // fp32 x,y per point
  __shared__ __align__(16) u16   hS  [4][2][16*80];// [wave][hi/lo plane][row*80 + swz col]
  __shared__ __align__(16) s16x8 wS  [10][64];     // shared lo-frags: B2l[c][s]->c*2+s, B3l[s]->8+s

  const int tid  = threadIdx.x;
  const int lane = tid & 63;
  const int wv   = tid >> 6;
  const int m    = lane & 15;   // A row / B,C col
  const int q    = lane >> 4;   // k-quad

  // ---- build B-frags from global fp32 weights (one-time; L2-cached) ----
  // Hot frags in registers: B1, B2h (both halves), B3h. Cold lo-frags in shared LDS.
  float w1x[4], w1y[4];
  s16x8 B1[4], B2h[4][2], B3h[2];
  #pragma unroll
  for (int c = 0; c < 4; ++c) {
    const int n = c*16 + m;
    w1x[c] = w1[n]; w1y[c] = w1[64 + n];
    s16x8 f1;
    #pragma unroll
    for (int j = 0; j < 8; ++j) {               // B1: feature rows 2..33, K=32 exactly
      const int k = q*8 + j;
      f1[j] = (short)f2bf(w1[(2 + k)*64 + n]);
    }
    B1[c] = f1;
    #pragma unroll
    for (int s = 0; s < 2; ++s) {
      s16x8 fh, fl;
      #pragma unroll
      for (int j = 0; j < 8; ++j) {
        const int k = s*32 + q*8 + j;
        const float v = w2[k*64 + n];
        const u16 h = f2bf(v);
        fh[j] = (short)h; fl[j] = (short)f2bf(v - bf2f(h));
      }
      B2h[c][s] = fh;
      if (wv == 0) wS[c*2 + s][lane] = fl;
    }
  }
  #pragma unroll
  for (int s = 0; s < 2; ++s) {
    s16x8 fh, fl;
    #pragma unroll
    for (int j = 0; j < 8; ++j) {
      const int k = s*32 + q*8 + j;
      const float v = (m < 3) ? w3[k*3 + m] : 0.f;
      const u16 h = f2bf(v);
      fh[j] = (short)h; fl[j] = (short)f2bf(v - bf2f(h));
    }
    B3h[s] = fh;
    if (wv == 0) wS[8 + s][lane] = fl;
  }
  __syncthreads();   // once, outside the main loop: publish wS to all waves

  u16* const hpl = &hS[wv][0][0];   // hi plane (this wave)
  u16* const lpl = &hS[wv][1][0];   // lo plane (this wave)
  const int mq8  = (m & 12) << 1;   // read-side swizzle key: data-row quad * 8

  for (int it = 0; it < iters; ++it) {
    const int base = (blockIdx.x * iters + it) << 8;   // 256 points / iteration

    // ---- phase A: per-thread fp32 encode -> bf16 feature row in LDS ----
    {
      const float2 xy = xq[base + tid];
      ((float2*)xyS)[tid] = xy;
      const float xf = xy.x, yf = xy.y;
      u32 er[16];
      if constexpr (PACKED) {
        // (1) hash levels 12..15: issue all 16 long-latency gathers FIRST
        u32 hv[4][4];
        #pragma unroll
        for (int l = 12; l < 16; ++l) {
          const int res = RESI[l];
          const u32 ix = (u32)floorf(xf * (float)res);
          const u32 iy = (u32)floorf(yf * (float)res);
          const u32 hy = iy * HPRIME, hy1 = hy + HPRIME;
          const u32* t = ctab + (size_t)l * TBL;
          hv[l-12][0] = t[( ix       ^ hy ) & TMASK];
          hv[l-12][1] = t[((ix + 1u) ^ hy ) & TMASK];
          hv[l-12][2] = t[( ix       ^ hy1) & TMASK];
          hv[l-12][3] = t[((ix + 1u) ^ hy1) & TMASK];
        }
        // (2) dense levels 0..11 (tables ~2.5MB packed: L1/L2-hot) while hash flies
        #pragma unroll
        for (int l = 0; l < 12; ++l) {
          const int res = RESI[l];
          const float px = xf * (float)res, py = yf * (float)res;
          const float fx = floorf(px), fy = floorf(py);
          const float wx = px - fx, wy = py - fy;
          const u32 ix = (u32)fx, iy = (u32)fy;
          const float w00 = (1.f-wx)*(1.f-wy), w10 = wx*(1.f-wy);
          const float w01 = (1.f-wx)*wy,       w11 = wx*wy;
          const u32 st  = (u32)res + 1u;
          const u32 i00 = ix + iy*st;
          const u32* t = ctab + (size_t)l * TBL;
          const u32x2a eA = *(const u32x2a*)&t[i00];        // e00 | e10
          const u32x2a eB = *(const u32x2a*)&t[i00 + st];   // e01 | e11
          const float f0 = blo(eA[0])*w00 + blo(eA[1])*w10 + blo(eB[0])*w01 + blo(eB[1])*w11;
          const float f1 = bhi(eA[0])*w00 + bhi(eA[1])*w10 + bhi(eB[0])*w01 + bhi(eB[1])*w11;
          er[l] = cvtpk(f0, f1);
        }
        // (3) consume hash gathers (weights recomputed: 16 regs cheaper than 24)
        #pragma unroll
        for (int hl = 0; hl < 4; ++hl) {
          const int res = RESI[12 + hl];
          const float px = xf * (float)res, py = yf * (float)res;
          const float wx = px - floorf(px), wy = py - floorf(py);
          const float w00 = (1.f-wx)*(1.f-wy), w10 = wx*(1.f-wy);
          const float w01 = (1.f-wx)*wy,       w11 = wx*wy;
          const float f0 = blo(hv[hl][0])*w00 + blo(hv[hl][1])*w10
                         + blo(hv[hl][2])*w01 + blo(hv[hl][3])*w11;
          const float f1 = bhi(hv[hl][0])*w00 + bhi(hv[hl][1])*w10
                         + bhi(hv[hl][2])*w01 + bhi(hv[hl][3])*w11;
          er[12 + hl] = cvtpk(f0, f1);
        }
      } else {
        #pragma unroll
        for (int l = 0; l < 16; ++l) {
          const int res = RESI[l];
          const float px = xf * (float)res, py = yf * (float)res;
          const float fx = floorf(px), fy = floorf(py);
          const float wx = px - fx, wy = py - fy;
          const u32 ix = (u32)fx, iy = (u32)fy;
          const float w00 = (1.f-wx)*(1.f-wy), w10 = wx*(1.f-wy);
          const float w01 = (1.f-wx)*wy,       w11 = wx*wy;
          float f0, f1;
          if (l < 12) {
            const u32 st  = (u32)res + 1u;
            const u32 i00 = ix + iy*st;
            const float2* t = tab32 + (size_t)l * TBL;
            const f32x4a eA = *(const f32x4a*)&t[i00];
            const f32x4a eB = *(const f32x4a*)&t[i00 + st];
            f0 = eA[0]*w00 + eA[2]*w10 + eB[0]*w01 + eB[2]*w11;
            f1 = eA[1]*w00 + eA[3]*w10 + eB[1]*w01 + eB[3]*w11;
          } else {
            const u32 hy = iy * HPRIME, hy1 = hy + HPRIME;
            const u32 i00 = ( ix        ^ hy ) & TMASK;
            const u32 i10 = ((ix + 1u)  ^ hy ) & TMASK;
            const u32 i01 = ( ix        ^ hy1) & TMASK;
            const u32 i11 = ((ix + 1u)  ^ hy1) & TMASK;
            const float2* t = tab32 + (size_t)l * TBL;
            const float2 e00 = t[i00], e10 = t[i10], e01 = t[i01], e11 = t[i11];
            f0 = e00.x*w00 + e10.x*w10 + e01.x*w01 + e11.x*w11;
            f1 = e00.y*w00 + e10.y*w10 + e01.y*w01 + e11.y*w11;
          }
          er[l] = cvtpk(f0, f1);
        }
      }
      uint4* rowp = (uint4*)&encS[tid * 40];
      rowp[0] = make_uint4(er[0],  er[1],  er[2],  er[3]);
      rowp[1] = make_uint4(er[4],  er[5],  er[6],  er[7]);
      rowp[2] = make_uint4(er[8],  er[9],  er[10], er[11]);
      rowp[3] = make_uint4(er[12], er[13], er[14], er[15]);
    }

    // ---- phase B: per-wave MFMA MLP, 4 tiles of 16 points (wave-private, no barriers) ----
    #pragma unroll 1
    for (int t4 = 0; t4 < 4; ++t4) {
      const int rbase = wv*64 + t4*16;
      const s16x8 a1 = *(const s16x8*)&encS[(rbase + m)*40 + q*8];

      float xr[4], yr[4];
      #pragma unroll
      for (int r = 0; r < 4; ++r) {
        const float2 v = ((const float2*)xyS)[rbase + q*4 + r];
        xr[r] = v.x; yr[r] = v.y;
      }

      f32x4 acc[4];
      #pragma unroll
      for (int c = 0; c < 4; ++c) {
        f32x4 z;
        #pragma unroll
        for (int r = 0; r < 4; ++r) z[r] = xr[r]*w1x[c] + yr[r]*w1y[c];  // fp32 x,y path
        acc[c] = MFMA(a1, B1[c], z);
      }

      // relu + hi/lo bf16 split -> swizzled u16 planes (writes spread over 16 banks)
      #pragma unroll
      for (int c = 0; c < 4; ++c)
        #pragma unroll
        for (int r = 0; r < 4; ++r) {
          const float h = fmaxf(acc[c][r], 0.f);
          const u32 hp_ = cvtpk(h, h);                                  // lo16 = bf16(h)
          const float lf = h - __builtin_bit_cast(float, hp_ << 16);
          const u32 lp_ = cvtpk(lf, lf);
          const int idx = (q*4 + r)*80 + ((c*16 + m) ^ (q << 3));
          hpl[idx] = (u16)hp_;
          lpl[idx] = (u16)lp_;
        }

      s16x8 hi0 = *(const s16x8*)&hpl[m*80 + ((q*8) ^ mq8)];
      s16x8 hi1 = *(const s16x8*)&hpl[m*80 + 32 + ((q*8) ^ mq8)];
      s16x8 lo0 = *(const s16x8*)&lpl[m*80 + ((q*8) ^ mq8)];
      s16x8 lo1 = *(const s16x8*)&lpl[m*80 + 32 + ((q*8) ^ mq8)];

      #pragma unroll
      for (int c = 0; c < 4; ++c) {
        const s16x8 b2l0 = wS[c*2 + 0][lane];   // cold lo-frags from shared LDS
        const s16x8 b2l1 = wS[c*2 + 1][lane];
        f32x4 z = {0.f,0.f,0.f,0.f};
        z = MFMA(hi0, B2h[c][0], z); z = MFMA(hi1, B2h[c][1], z);
        z = MFMA(lo0, B2h[c][0], z); z = MFMA(lo1, B2h[c][1], z);
        z = MFMA(hi0, b2l0,      z); z = MFMA(hi1, b2l1,      z);
        acc[c] = z;
      }

      #pragma unroll
      for (int c = 0; c < 4; ++c)
        #pragma unroll
        for (int r = 0; r < 4; ++r) {
          const float h = fmaxf(acc[c][r], 0.f);
          const u32 hp_ = cvtpk(h, h);
          const float lf = h - __builtin_bit_cast(float, hp_ << 16);
          const u32 lp_ = cvtpk(lf, lf);
          const int idx = (q*4 + r)*80 + ((c*16 + m) ^ (q << 3));
          hpl[idx] = (u16)hp_;
          lpl[idx] = (u16)lp_;
        }

      hi0 = *(const s16x8*)&hpl[m*80 + ((q*8) ^ mq8)];
      hi1 = *(const s16x8*)&hpl[m*80 + 32 + ((q*8) ^ mq8)];
      lo0 = *(const s16x8*)&lpl[m*80 + ((q*8) ^ mq8)];
      lo1 = *(const s16x8*)&lpl[m*80 + 32 + ((q*8) ^ mq8)];

      const s16x8 b3l0 = wS[8][lane];
      const s16x8 b3l1 = wS[9][lane];
      f32x4 z = {0.f,0.f,0.f,0.f};
      z = MFMA(hi0, B3h[0], z); z = MFMA(hi1, B3h[1], z);
      z = MFMA(lo0, B3h[0], z); z = MFMA(lo1, B3h[1], z);
      z = MFMA(hi0, b3l0,   z); z = MFMA(hi1, b3l1,   z);

      if (m < 3) {   // C: row = q*4+r, col = m
        #pragma unroll
        for (int r = 0; r < 4; ++r)
          out[(size_t)(base + rbase + q*4 + r)*3 + m] = z[r];
      }
    }
  }
}

extern "C" void kernel_launch(void* const* d_in, const int* in_sizes, int n_in,
                              void* d_out, int out_size, void* d_ws, size_t ws_size,
                              hipStream_t stream) {
  const int N = in_sizes[0] / 2;            // 2^21 points
  const int ITERS = 4;
  const int blocks = N / (256 * ITERS);     // 2048 blocks
  const size_t ctab_bytes = (size_t)16 * TBL * 4;   // 32 MB packed-bf16 tables
  if (ws_size >= ctab_bytes) {
    cvt_tab<<<2048, 256, 0, stream>>>((const float4*)d_in[1], (uint2*)d_ws, (int)(16*TBL/2));
    ngp_fused<true><<<blocks, 256, 0, stream>>>(
        (const float2*)d_in[0], (const float2*)d_in[1], (const u32*)d_ws,
        (const float*)d_in[2], (const float*)d_in[3], (const float*)d_in[4],
        (float*)d_out, ITERS);
  } else {
    ngp_fused<false><<<blocks, 256, 0, stream>>>(
        (const float2*)d_in[0], (const float2*)d_in[1], (const u32*)d_ws,
        (const float*)d_in[2], (const float*)d_in[3], (const float*)d_in[4],
        (float*)d_out, ITERS);
  }
}